// Round 16
// baseline (265.604 us; speedup 1.0000x reference)
//
#include <hip/hip_runtime.h>
#include <hip/hip_bf16.h>
#include <stdint.h>

typedef unsigned short u16;
typedef __bf16 bf16x8 __attribute__((ext_vector_type(8)));
typedef float f32x4 __attribute__((ext_vector_type(4)));

#define SEQ    2048
#define DMODEL 2048
#define NHEAD  16
#define DHEAD  128
// 1/sqrt(128) * log2(e): Q pre-scaled so QK^T lands directly in exp2 domain
#define QSCALE (0.088388347648318447f * 1.4426950408889634f)

__device__ __forceinline__ u16 f2bf(float f){
  uint32_t u = __float_as_uint(f);
  u += 0x7FFFu + ((u >> 16) & 1u);        // round-to-nearest-even
  return (u16)(u >> 16);
}

__device__ __forceinline__ void gload_lds16(const u16* g, u16* l){
  __builtin_amdgcn_global_load_lds((const __attribute__((address_space(1))) void*)g,
                                   (__attribute__((address_space(3))) void*)l,
                                   16, 0, 0);
}

// ---------------- f32 -> bf16 conversion (x + all 4 weights, one launch) ----
__global__ __launch_bounds__(256) void cvt_all(const float* __restrict__ x,
    const float* __restrict__ Wq, const float* __restrict__ Wk,
    const float* __restrict__ Wv, const float* __restrict__ Wo,
    u16* __restrict__ dst){
  int gid = blockIdx.x * 256 + threadIdx.x;   // 6291456 float4 groups total
  const float* s; int idx;
  if (gid < 2097152){ s = x; idx = gid; }
  else {
    int j = gid - 2097152;
    int z = j >> 20; idx = j & 0xFFFFF;
    s = (z==0) ? Wq : (z==1) ? Wk : (z==2) ? Wv : Wo;
  }
  float4 v = reinterpret_cast<const float4*>(s)[idx];
  ushort4 o;
  o.x = f2bf(v.x); o.y = f2bf(v.y); o.z = f2bf(v.z); o.w = f2bf(v.w);
  reinterpret_cast<ushort4*>(dst)[gid] = o;
}

// ============ shared GEMM pieces (validated) ============
__device__ __forceinline__ void stageA(const u16* __restrict__ G, int grow0, int kt,
                                       int half, u16* lds, int w, int lane){
  #pragma unroll
  for (int j = 0; j < 2; ++j){
    int q   = w*2 + j;                                   // 0..15
    int r0  = ((q & 8) << 4) + half*64 + (q & 7)*8;      // 8-row group start
    int row = r0 + (lane >> 3);
    int sc  = (lane & 7) ^ (row & 7);                    // inverse swizzle
    gload_lds16(G + (size_t)(grow0 + row)*DMODEL + kt*64 + sc*8, lds + r0*64);
  }
}

__device__ __forceinline__ bf16x8 ldsf(const u16* lds, int row, int c){
  return *reinterpret_cast<const bf16x8*>(lds + row*64 + (((c ^ (row & 7)) & 7) << 3));
}

template<int MH>
__device__ __forceinline__ void load_a(bf16x8 (&a)[4][2], const u16* LA,
                                       int wr, int ln, int g){
  #pragma unroll
  for (int m = 0; m < 4; ++m){
    int row = wr*128 + MH*64 + m*16 + ln;
    a[m][0] = ldsf(LA, row, g);
    a[m][1] = ldsf(LA, row, 4 + g);
  }
}

// phase_pre v2: barrier + scheduling fence only (validated neutral r13).
__device__ __forceinline__ void phase_pre(){
  __builtin_amdgcn_s_barrier();
  __builtin_amdgcn_sched_barrier(0);
}

// ============ 256x128 2-phase GEMM core (validated r9/out3) ============
__device__ __forceinline__ void stageB3(const u16* __restrict__ G, int grow0,
    int kt, u16* lds, int w, int lane){
  #pragma unroll
  for (int j = 0; j < 2; ++j){
    int q   = w*2 + j;
    int r0  = q*8;
    int row = r0 + (lane >> 3);
    int sc  = (lane & 7) ^ (row & 7);
    gload_lds16(G + (size_t)(grow0 + row)*DMODEL + kt*64 + sc*8, lds + r0*64);
  }
}

__device__ __forceinline__ void load_b3(bf16x8 (&b)[2][2], const u16* LB,
                                        int wc, int ln, int g){
  #pragma unroll
  for (int n = 0; n < 2; ++n){
    int row = wc*32 + n*16 + ln;
    b[n][0] = ldsf(LB, row, g);
    b[n][1] = ldsf(LB, row, 4 + g);
  }
}

template<int MH>
__device__ __forceinline__ void mfma8x2(f32x4 (&acc)[8][2], bf16x8 (&a)[4][2],
                                        bf16x8 (&b)[2][2]){
  __builtin_amdgcn_s_setprio(1);
  #pragma unroll
  for (int m = 0; m < 4; ++m)
    #pragma unroll
    for (int n = 0; n < 2; ++n){
      acc[MH*4+m][n] = __builtin_amdgcn_mfma_f32_16x16x32_bf16(
          a[m][0], b[n][0], acc[MH*4+m][n], 0, 0, 0);
      acc[MH*4+m][n] = __builtin_amdgcn_mfma_f32_16x16x32_bf16(
          a[m][1], b[n][1], acc[MH*4+m][n], 0, 0, 0);
    }
  __builtin_amdgcn_s_setprio(0);
}

__device__ __forceinline__ void gemm128_core(const u16* __restrict__ A,
    const u16* __restrict__ W, int bm, int bnl,
    u16 (*ldsA)[256*64], u16 (*ldsB)[128*64], f32x4 (&acc)[8][2],
    int w, int lane, int wr, int wc, int g, int ln){
  {
    const f32x4 z4 = {0.f,0.f,0.f,0.f};
    #pragma unroll
    for (int i = 0; i < 8; ++i){ acc[i][0] = z4; acc[i][1] = z4; }
  }
  stageA (A, bm,  0, 0, ldsA[0], w, lane);
  stageA (A, bm,  0, 1, ldsA[0], w, lane);
  stageB3(W, bnl, 0,    ldsB[0], w, lane);
  stageA (A, bm,  1, 0, ldsA[1], w, lane);
  asm volatile("s_waitcnt vmcnt(2)" ::: "memory");
  __builtin_amdgcn_s_barrier();

  bf16x8 a[4][2], b[2][2];
  const int NT = DMODEL/64;   // 32
  for (int t = 0; t < NT; ++t){
    const int cur = t & 1;
    const u16* LA = ldsA[cur];
    const u16* LB = ldsB[cur];
    load_a<0>(a, LA, wr, ln, g);
    load_b3(b, LB, wc, ln, g);
    if (t+1 < NT){
      stageA (A, bm,  t+1, 1, ldsA[cur^1], w, lane);
      stageB3(W, bnl, t+1,    ldsB[cur^1], w, lane);
    }
    phase_pre();
    mfma8x2<0>(acc, a, b);
    __builtin_amdgcn_s_barrier();
    load_a<1>(a, LA, wr, ln, g);
    if (t+2 < NT) stageA(A, bm, t+2, 0, ldsA[cur], w, lane);
    if (t < NT-2) { asm volatile("s_waitcnt vmcnt(2)" ::: "memory"); }
    else          { asm volatile("s_waitcnt vmcnt(0)" ::: "memory"); }
    phase_pre();
    mfma8x2<1>(acc, a, b);
    __builtin_amdgcn_s_barrier();
  }
}

// Fused QKV on the out3 core: grid 768 (16 mt x 48 nt) = exactly 3.0
// rounds of 256 CUs. nt = swz>>4 in [xcd*6, xcd*6+6): 3MB B-panel per XCD
// (L2-fit). BN=128 divides 2048 -> z = nt>>4 is block-uniform.
__global__ __launch_bounds__(512, 2) void gemm_qkv128(const u16* __restrict__ A,
    const u16* __restrict__ Wall, u16* __restrict__ Q, u16* __restrict__ Kb,
    u16* __restrict__ Vt){
  __shared__ __align__(16) u16 ldsA[2][256*64];  // 64KB
  __shared__ __align__(16) u16 ldsB[2][128*64];  // 32KB
  const int tid = threadIdx.x, w = tid >> 6, lane = tid & 63;
  const int g = lane >> 4, ln = lane & 15;
  const int wr = w >> 2, wc = w & 3;
  const int bid = blockIdx.x;
  const int swz = (bid & 7)*96 + (bid >> 3);      // XCD-bijective (768 = 8*96)
  const int nt = swz >> 4, mt = swz & 15;         // nt-major per XCD: B-panel reuse
  const int bm = mt*256, bnl = nt << 7;
  const int z  = nt >> 4;                         // block-uniform output select
  const u16* W = Wall + ((size_t)z << 22);
  const int bnw = bnl & 2047;                     // col base within W_z / output
  f32x4 acc[8][2];
  gemm128_core(A, W, bm, bnw, ldsA, ldsB, acc, w, lane, wr, wc, g, ln);

  if (z < 2){
    u16* C = (z == 0) ? Q : Kb;
    const float sc = (z == 0) ? QSCALE : 1.0f;
    #pragma unroll
    for (int mf = 0; mf < 8; ++mf)
      #pragma unroll
      for (int nf = 0; nf < 2; ++nf){
        int col = bnw + wc*32 + nf*16 + ln;
        #pragma unroll
        for (int i = 0; i < 4; ++i){
          int row = bm + wr*128 + mf*16 + g*4 + i;
          C[(size_t)row*DMODEL + col] = f2bf(acc[mf][nf][i] * sc);
        }
      }
  } else {
    #pragma unroll
    for (int mf = 0; mf < 8; ++mf)
      #pragma unroll
      for (int nf = 0; nf < 2; ++nf){
        int col  = bnw + wc*32 + nf*16 + ln;     // h*128 + d
        int row0 = bm + wr*128 + mf*16 + g*4;    // 4 consecutive tokens
        int bb   = row0 >> 11, lt = row0 & (SEQ-1);
        ushort4 pk;
        pk.x = f2bf(acc[mf][nf][0]); pk.y = f2bf(acc[mf][nf][1]);
        pk.z = f2bf(acc[mf][nf][2]); pk.w = f2bf(acc[mf][nf][3]);
        *reinterpret_cast<ushort4*>(Vt + (size_t)(bb*DMODEL + col)*SEQ + lt) = pk;
      }
  }
}

// Output projection (validated r9): grid 256 = 1.0 block/CU.
__global__ __launch_bounds__(512, 2) void gemm_out3(const u16* __restrict__ A,
    const u16* __restrict__ Wo, float* __restrict__ C){
  __shared__ __align__(16) u16 ldsA[2][256*64];  // 64KB
  __shared__ __align__(16) u16 ldsB[2][128*64];  // 32KB
  const int tid = threadIdx.x, w = tid >> 6, lane = tid & 63;
  const int g = lane >> 4, ln = lane & 15;
  const int wr = w >> 2, wc = w & 3;
  const int bid = blockIdx.x;
  const int x = bid & 7, s = bid >> 3;            // XCD-bijective, mt-major
  const int mt = s >> 1, nt = 2*x + (s & 1);
  const int bm = mt*256, bnl = nt << 7;           // BN = 128
  f32x4 acc[8][2];
  gemm128_core(A, Wo, bm, bnl, ldsA, ldsB, acc, w, lane, wr, wc, g, ln);
  #pragma unroll
  for (int mf = 0; mf < 8; ++mf)
    #pragma unroll
    for (int nf = 0; nf < 2; ++nf){
      int col = bnl + wc*32 + nf*16 + ln;
      #pragma unroll
      for (int i = 0; i < 4; ++i){
        int row = bm + wr*128 + mf*16 + g*4 + i;
        C[(size_t)row*DMODEL + col] = acc[mf][nf][i];
      }
    }
}

// ================= causal flash attention v5 (r13 exact, best) ======
__device__ __forceinline__ void attn_stageK(const u16* __restrict__ Kb,
    u16* Kt, int b, int h, int kb, int w, int lane){
  #pragma unroll
  for (int is = 0; is < 4; ++is){
    int o = w*4096 + is*1024 + lane*16;
    int row = o >> 8;                          // K rows: 256B each
    int sc  = ((o >> 4) & 15) ^ (row & 7);
    gload_lds16(Kb + (size_t)(b*SEQ + kb + row)*DMODEL + h*DHEAD + sc*8,
                Kt + w*2048 + is*512);
  }
}
__device__ __forceinline__ void attn_stageV(const u16* __restrict__ Vtb,
    u16* Vt, int bh, int kb, int w, int lane){
  #pragma unroll
  for (int is = 0; is < 4; ++is){
    int o = w*4096 + is*1024 + lane*16;
    int row = o >> 7;                          // V^T rows: 128B each
    int sc  = ((o >> 4) & 7) ^ (row & 7);
    gload_lds16(Vtb + (size_t)(bh*DHEAD + row)*SEQ + kb + sc*8,
                Vt + w*2048 + is*512);
  }
}

template<bool MASKED>
__device__ __forceinline__ void attn_qkt_sm(const u16* Kt, u16* Pw,
    const bf16x8 (&qf)[2][4], f32x4 (&yacc)[2][8],
    float (&mrun)[2], float (&lrun)[2],
    int kb, int qg0, int g, int ln){
  #pragma unroll
  for (int qc = 0; qc < 2; ++qc){
    f32x4 st[4];
    __builtin_amdgcn_s_setprio(1);
    #pragma unroll
    for (int kt = 0; kt < 4; ++kt){
      f32x4 accs = {0.f,0.f,0.f,0.f};
      #pragma unroll
      for (int c = 0; c < 4; ++c){
        int row = kt*16 + ln;
        int ch  = (c*4 + g) ^ (row & 7);
        bf16x8 kf = *reinterpret_cast<const bf16x8*>(Kt + row*128 + ch*8);
        accs = __builtin_amdgcn_mfma_f32_16x16x32_bf16(kf, qf[qc][c], accs, 0, 0, 0);
      }
      st[kt] = accs;
    }
    __builtin_amdgcn_s_setprio(0);

    const int qg = qg0 + qc*16;
    float p[16];
    float tmax = -1e30f;
    #pragma unroll
    for (int kt = 0; kt < 4; ++kt)
      #pragma unroll
      for (int i = 0; i < 4; ++i){
        float s = st[kt][i];
        if (MASKED && (kb + kt*16 + g*4 + i) > qg) s = -1e30f;
        p[kt*4+i] = s;
        tmax = fmaxf(tmax, s);
      }
    tmax = fmaxf(tmax, __shfl_xor(tmax, 16));
    tmax = fmaxf(tmax, __shfl_xor(tmax, 32));

    if (!__all(tmax - mrun[qc] <= 11.5f)){
      float mn = fmaxf(mrun[qc], tmax);
      float fr = __builtin_amdgcn_exp2f(mrun[qc] - mn);
      lrun[qc] *= fr;
      float fi[4];
      #pragma unroll
      for (int i = 0; i < 4; ++i) fi[i] = __shfl(fr, g*4 + i);
      #pragma unroll
      for (int dt = 0; dt < 8; ++dt)
        #pragma unroll
        for (int i = 0; i < 4; ++i) yacc[qc][dt][i] *= fi[i];
      mrun[qc] = mn;
    }
    float psum = 0.f;
    #pragma unroll
    for (int j = 0; j < 16; ++j){
      p[j] = __builtin_amdgcn_exp2f(p[j] - mrun[qc]);
      psum += p[j];
    }
    psum += __shfl_xor(psum, 16);
    psum += __shfl_xor(psum, 32);
    lrun[qc] += psum;

    char* pb = reinterpret_cast<char*>(Pw + qc*1024);
    #pragma unroll
    for (int kt = 0; kt < 4; ++kt)
      #pragma unroll
      for (int pr = 0; pr < 2; ++pr){
        uint32_t pk = (uint32_t)f2bf(p[kt*4 + 2*pr]) |
                      ((uint32_t)f2bf(p[kt*4 + 2*pr + 1]) << 16);
        int byte = (kt*16 + g*4 + 2*pr)*2;
        int ch   = (byte >> 4) ^ (ln & 7);
        int addr = ln*128 + (ch << 4) + (byte & 15);
        *reinterpret_cast<uint32_t*>(pb + addr) = pk;
      }
  }
}

__device__ __forceinline__ void attn_pv(const u16* Vt, const u16* Pw,
                                        f32x4 (&yacc)[2][8], int g, int ln){
  __builtin_amdgcn_s_setprio(1);
  #pragma unroll
  for (int kc = 0; kc < 2; ++kc){
    int chp = (kc*4 + g) ^ (ln & 7);
    bf16x8 pf0 = *reinterpret_cast<const bf16x8*>(Pw +        ln*64 + chp*8);
    bf16x8 pf1 = *reinterpret_cast<const bf16x8*>(Pw + 1024 + ln*64 + chp*8);
    #pragma unroll
    for (int dt = 0; dt < 8; ++dt){
      int row = dt*16 + ln;
      int chv = (kc*4 + g) ^ (row & 7);
      bf16x8 vf = *reinterpret_cast<const bf16x8*>(Vt + row*64 + chv*8);
      yacc[0][dt] = __builtin_amdgcn_mfma_f32_16x16x32_bf16(pf0, vf, yacc[0][dt], 0, 0, 0);
      yacc[1][dt] = __builtin_amdgcn_mfma_f32_16x16x32_bf16(pf1, vf, yacc[1][dt], 0, 0, 0);
    }
  }
  __builtin_amdgcn_s_setprio(0);
}

__global__ __launch_bounds__(256, 2) void attn_fwd(const u16* __restrict__ Qb,
    const u16* __restrict__ Kb, const u16* __restrict__ Vtb, u16* __restrict__ Yb){
  __shared__ __align__(16) u16 Kt[2][64*128];  // 32KB
  __shared__ __align__(16) u16 Vt[2][128*64];  // 32KB
  __shared__ __align__(16) u16 Pl[4][2048];    // 16KB
  const int tid = threadIdx.x, w = tid >> 6, lane = tid & 63;
  const int g = lane >> 4, ln = lane & 15;
  // XCD-chunked mapping (bijective over 512 blocks):
  const int bid = blockIdx.x;
  const int xcd = bid & 7, idx = bid >> 3;
  const int slot = idx >> 4, j = idx & 15;
  const int x = (j & 1) ? (15 - (j >> 1)) : (j >> 1);   // pairs {i,15-i}
  const int bh = (slot < 2) ? (xcd*2 + slot) : (xcd*2 + 14 + slot);
  const int b = bh >> 4, h = bh & 15;
  const int qb = (bh < 16) ? x : (15 - x);              // constant-sum balance
  const int qw = qb*128 + w*32;
  const int qg0 = qw + ln;
  const int NT = 2*qb + 2;

  bf16x8 qf[2][4];
  #pragma unroll
  for (int qc = 0; qc < 2; ++qc){
    const u16* qp = Qb + (size_t)(b*SEQ + qw + qc*16 + ln)*DMODEL + h*DHEAD + g*8;
    #pragma unroll
    for (int c = 0; c < 4; ++c) qf[qc][c] = *reinterpret_cast<const bf16x8*>(qp + c*32);
  }
  float mrun[2] = {-1e30f, -1e30f}, lrun[2] = {0.f, 0.f};
  f32x4 yacc[2][8];
  {
    const f32x4 z4 = {0.f,0.f,0.f,0.f};
    #pragma unroll
    for (int qc = 0; qc < 2; ++qc)
      #pragma unroll
      for (int dt = 0; dt < 8; ++dt) yacc[qc][dt] = z4;
  }
  u16* Pw = &Pl[w][0];

  attn_stageK(Kb, &Kt[0][0], b, h, 0, w, lane);
  attn_stageV(Vtb, &Vt[0][0], bh, 0, w, lane);
  asm volatile("s_waitcnt vmcnt(0)" ::: "memory");
  __builtin_amdgcn_s_barrier();

  int cur = 0;
  for (int t = 0; t < NT; ++t){
    const int kb = t*64;
    if (t+1 < NT){
      attn_stageK(Kb, &Kt[cur^1][0], b, h, kb + 64, w, lane);
      attn_stageV(Vtb, &Vt[cur^1][0], bh, kb + 64, w, lane);
    }
    bool active = true;
    if (t < NT-2){
      attn_qkt_sm<false>(&Kt[cur][0], Pw, qf, yacc, mrun, lrun, kb, qg0, g, ln);
    } else if (t == NT-2){
      if (w >= 2) attn_qkt_sm<false>(&Kt[cur][0], Pw, qf, yacc, mrun, lrun, kb, qg0, g, ln);
      else        attn_qkt_sm<true >(&Kt[cur][0], Pw, qf, yacc, mrun, lrun, kb, qg0, g, ln);
    } else {
      if (w >= 2) attn_qkt_sm<true >(&Kt[cur][0], Pw, qf, yacc, mrun, lrun, kb, qg0, g, ln);
      else        active = false;
    }
    if (active) attn_pv(&Vt[cur][0], Pw, yacc, g, ln);
    asm volatile("s_waitcnt vmcnt(0) lgkmcnt(0)" ::: "memory");
    __builtin_amdgcn_s_barrier();
    cur ^= 1;
  }

  #pragma unroll
  for (int qc = 0; qc < 2; ++qc){
    float inv[4];
    #pragma unroll
    for (int i = 0; i < 4; ++i){
      float li = __shfl(lrun[qc], g*4 + i);
      inv[i] = __builtin_amdgcn_rcpf(li);
    }
    #pragma unroll
    for (int dt = 0; dt < 8; ++dt)
      #pragma unroll
      for (int i = 0; i < 4; ++i){
        Yb[(size_t)(b*SEQ + qw + qc*16 + g*4 + i)*DMODEL + h*DHEAD + dt*16 + ln] =
            f2bf(yacc[qc][dt][i] * inv[i]);
      }
  }
}

// ---------------- launcher ----------------
extern "C" void kernel_launch(void* const* d_in, const int* in_sizes, int n_in,
                              void* d_out, int out_size, void* d_ws, size_t ws_size,
                              hipStream_t stream) {
  const float* x  = (const float*)d_in[0];
  const float* Wq = (const float*)d_in[1];
  const float* Wk = (const float*)d_in[2];
  const float* Wv = (const float*)d_in[3];
  const float* Wo = (const float*)d_in[4];
  float* out = (float*)d_out;

  char* ws = (char*)d_ws;
  u16* xb  = (u16*)(ws +          0);
  u16* Wqb = (u16*)(ws + 16777216);    // Wq/Wk/Wv/Wo contiguous (32MB)
  u16* Wob = (u16*)(ws + 41943040);
  u16* Qb  = (u16*)(ws + 50331648);
  u16* Kb  = (u16*)(ws + 67108864);
  u16* Vtb = (u16*)(ws + 83886080);
  u16* Yb  = (u16*)(ws + 100663296);

  cvt_all<<<dim3(24576), 256, 0, stream>>>(x, Wq, Wk, Wv, Wo, xb);

  gemm_qkv128<<<dim3(768), 512, 0, stream>>>(xb, Wqb, Qb, Kb, Vtb);

  attn_fwd<<<dim3(512), 256, 0, stream>>>(Qb, Kb, Vtb, Yb);

  gemm_out3<<<dim3(256), 512, 0, stream>>>(Yb, Wob, out);
}

// Round 17
// 250.477 us; speedup vs baseline: 1.0604x; 1.0604x over previous
//
#include <hip/hip_runtime.h>
#include <hip/hip_bf16.h>
#include <stdint.h>

typedef unsigned short u16;
typedef __bf16 bf16x8 __attribute__((ext_vector_type(8)));
typedef float f32x4 __attribute__((ext_vector_type(4)));

#define SEQ    2048
#define DMODEL 2048
#define NHEAD  16
#define DHEAD  128
// 1/sqrt(128) * log2(e): Q pre-scaled so QK^T lands directly in exp2 domain
#define QSCALE (0.088388347648318447f * 1.4426950408889634f)

__device__ __forceinline__ u16 f2bf(float f){
  uint32_t u = __float_as_uint(f);
  u += 0x7FFFu + ((u >> 16) & 1u);        // round-to-nearest-even
  return (u16)(u >> 16);
}

__device__ __forceinline__ void gload_lds16(const u16* g, u16* l){
  __builtin_amdgcn_global_load_lds((const __attribute__((address_space(1))) void*)g,
                                   (__attribute__((address_space(3))) void*)l,
                                   16, 0, 0);
}

// ---------------- f32 -> bf16 conversion (x + all 4 weights, one launch) ----
__global__ __launch_bounds__(256) void cvt_all(const float* __restrict__ x,
    const float* __restrict__ Wq, const float* __restrict__ Wk,
    const float* __restrict__ Wv, const float* __restrict__ Wo,
    u16* __restrict__ dst){
  int gid = blockIdx.x * 256 + threadIdx.x;   // 6291456 float4 groups total
  const float* s; int idx;
  if (gid < 2097152){ s = x; idx = gid; }
  else {
    int j = gid - 2097152;
    int z = j >> 20; idx = j & 0xFFFFF;
    s = (z==0) ? Wq : (z==1) ? Wk : (z==2) ? Wv : Wo;
  }
  float4 v = reinterpret_cast<const float4*>(s)[idx];
  ushort4 o;
  o.x = f2bf(v.x); o.y = f2bf(v.y); o.z = f2bf(v.z); o.w = f2bf(v.w);
  reinterpret_cast<ushort4*>(dst)[gid] = o;
}

// ============ shared GEMM pieces (validated) ============
__device__ __forceinline__ void stageA(const u16* __restrict__ G, int grow0, int kt,
                                       int half, u16* lds, int w, int lane){
  #pragma unroll
  for (int j = 0; j < 2; ++j){
    int q   = w*2 + j;                                   // 0..15
    int r0  = ((q & 8) << 4) + half*64 + (q & 7)*8;      // 8-row group start
    int row = r0 + (lane >> 3);
    int sc  = (lane & 7) ^ (row & 7);                    // inverse swizzle
    gload_lds16(G + (size_t)(grow0 + row)*DMODEL + kt*64 + sc*8, lds + r0*64);
  }
}

__device__ __forceinline__ bf16x8 ldsf(const u16* lds, int row, int c){
  return *reinterpret_cast<const bf16x8*>(lds + row*64 + (((c ^ (row & 7)) & 7) << 3));
}

template<int MH>
__device__ __forceinline__ void load_a(bf16x8 (&a)[4][2], const u16* LA,
                                       int wr, int ln, int g){
  #pragma unroll
  for (int m = 0; m < 4; ++m){
    int row = wr*128 + MH*64 + m*16 + ln;
    a[m][0] = ldsf(LA, row, g);
    a[m][1] = ldsf(LA, row, 4 + g);
  }
}

// phase_pre v2: barrier + scheduling fence only (validated neutral r13).
__device__ __forceinline__ void phase_pre(){
  __builtin_amdgcn_s_barrier();
  __builtin_amdgcn_sched_barrier(0);
}

// ============ 256x192 2-phase GEMM (fused QKV, validated r10/r13) ============
__device__ __forceinline__ void stageB192(const u16* __restrict__ G, int grow0,
    int kt, u16* lds, int w, int lane){
  #pragma unroll
  for (int j = 0; j < 3; ++j){
    int q   = w*3 + j;            // 0..23
    int r0  = q*8;                // 192 rows as 24 x 8-row groups
    int row = r0 + (lane >> 3);
    int sc  = (lane & 7) ^ (row & 7);
    gload_lds16(G + (size_t)(grow0 + row)*DMODEL + kt*64 + sc*8, lds + r0*64);
  }
}

__device__ __forceinline__ void load_b192(bf16x8 (&b)[3][2], const u16* LB,
                                          int wc, int ln, int g){
  #pragma unroll
  for (int n = 0; n < 3; ++n){
    int row = wc*48 + n*16 + ln;
    b[n][0] = ldsf(LB, row, g);
    b[n][1] = ldsf(LB, row, 4 + g);
  }
}

template<int MH>
__device__ __forceinline__ void mfma8x3(f32x4 (&acc)[8][3], bf16x8 (&a)[4][2],
                                        bf16x8 (&b)[3][2]){
  __builtin_amdgcn_s_setprio(1);
  #pragma unroll
  for (int m = 0; m < 4; ++m)
    #pragma unroll
    for (int n = 0; n < 3; ++n){
      acc[MH*4+m][n] = __builtin_amdgcn_mfma_f32_16x16x32_bf16(
          a[m][0], b[n][0], acc[MH*4+m][n], 0, 0, 0);
      acc[MH*4+m][n] = __builtin_amdgcn_mfma_f32_16x16x32_bf16(
          a[m][1], b[n][1], acc[MH*4+m][n], 0, 0, 0);
    }
  __builtin_amdgcn_s_setprio(0);
}

__global__ __launch_bounds__(512, 1) void gemm_qkv192(const u16* __restrict__ A,
    const u16* __restrict__ Wall, u16* __restrict__ Q, u16* __restrict__ Kb,
    u16* __restrict__ Vt){
  __shared__ __align__(16) u16 ldsA[2][256*64];  // 64KB
  __shared__ __align__(16) u16 ldsB[2][192*64];  // 48KB
  const int tid = threadIdx.x, w = tid >> 6, lane = tid & 63;
  const int g = lane >> 4, ln = lane & 15;
  const int wr = w >> 2, wc = w & 3;
  const int bid = blockIdx.x;
  const int swz = (bid & 7)*64 + (bid >> 3);      // XCD-bijective (512 = 8*64)
  const int nt = swz >> 4, mt = swz & 15;         // nt-major per XCD: B-panel reuse
  const int bm = mt*256, bnl = nt*192;
  f32x4 acc[8][3];
  {
    const f32x4 z4 = {0.f,0.f,0.f,0.f};
    #pragma unroll
    for (int i = 0; i < 8; ++i)
      #pragma unroll
      for (int j = 0; j < 3; ++j) acc[i][j] = z4;
  }
  stageA  (A,    bm,  0, 0, ldsA[0], w, lane);
  stageA  (A,    bm,  0, 1, ldsA[0], w, lane);
  stageB192(Wall, bnl, 0,    ldsB[0], w, lane);
  stageA  (A,    bm,  1, 0, ldsA[1], w, lane);
  asm volatile("s_waitcnt vmcnt(2)" ::: "memory");
  __builtin_amdgcn_s_barrier();

  bf16x8 a[4][2], b[3][2];
  const int NT = DMODEL/64;   // 32
  for (int t = 0; t < NT; ++t){
    const int cur = t & 1;
    const u16* LA = ldsA[cur];
    const u16* LB = ldsB[cur];
    load_a<0>(a, LA, wr, ln, g);
    load_b192(b, LB, wc, ln, g);
    if (t+1 < NT){
      stageA  (A,    bm,  t+1, 1, ldsA[cur^1], w, lane);
      stageB192(Wall, bnl, t+1,    ldsB[cur^1], w, lane);
    }
    phase_pre();
    mfma8x3<0>(acc, a, b);
    __builtin_amdgcn_s_barrier();
    load_a<1>(a, LA, wr, ln, g);
    if (t+2 < NT) stageA(A, bm, t+2, 0, ldsA[cur], w, lane);
    if (t < NT-2) { asm volatile("s_waitcnt vmcnt(2)" ::: "memory"); }
    else          { asm volatile("s_waitcnt vmcnt(0)" ::: "memory"); }
    phase_pre();
    mfma8x3<1>(acc, a, b);
    __builtin_amdgcn_s_barrier();
  }

  #pragma unroll
  for (int mf = 0; mf < 8; ++mf)
    #pragma unroll
    for (int nf = 0; nf < 3; ++nf){
      int col = bnl + wc*48 + nf*16 + ln;
      int z   = col >> 11;
      int c2  = col & 2047;
      if (z < 2){
        u16* C = (z == 0) ? Q : Kb;
        const float sc = (z == 0) ? QSCALE : 1.0f;
        #pragma unroll
        for (int i = 0; i < 4; ++i){
          int row = bm + wr*128 + mf*16 + g*4 + i;
          C[(size_t)row*DMODEL + c2] = f2bf(acc[mf][nf][i] * sc);
        }
      } else {
        int row0 = bm + wr*128 + mf*16 + g*4;
        int bb   = row0 >> 11, lt = row0 & (SEQ-1);
        ushort4 pk;
        pk.x = f2bf(acc[mf][nf][0]); pk.y = f2bf(acc[mf][nf][1]);
        pk.z = f2bf(acc[mf][nf][2]); pk.w = f2bf(acc[mf][nf][3]);
        *reinterpret_cast<ushort4*>(Vt + (size_t)(bb*DMODEL + c2)*SEQ + lt) = pk;
      }
    }
}

// ============ 256x128 2-phase GEMM (output projection, validated r9) ======
__device__ __forceinline__ void stageB3(const u16* __restrict__ G, int grow0,
    int kt, u16* lds, int w, int lane){
  #pragma unroll
  for (int j = 0; j < 2; ++j){
    int q   = w*2 + j;
    int r0  = q*8;
    int row = r0 + (lane >> 3);
    int sc  = (lane & 7) ^ (row & 7);
    gload_lds16(G + (size_t)(grow0 + row)*DMODEL + kt*64 + sc*8, lds + r0*64);
  }
}

__device__ __forceinline__ void load_b3(bf16x8 (&b)[2][2], const u16* LB,
                                        int wc, int ln, int g){
  #pragma unroll
  for (int n = 0; n < 2; ++n){
    int row = wc*32 + n*16 + ln;
    b[n][0] = ldsf(LB, row, g);
    b[n][1] = ldsf(LB, row, 4 + g);
  }
}

template<int MH>
__device__ __forceinline__ void mfma8x2(f32x4 (&acc)[8][2], bf16x8 (&a)[4][2],
                                        bf16x8 (&b)[2][2]){
  __builtin_amdgcn_s_setprio(1);
  #pragma unroll
  for (int m = 0; m < 4; ++m)
    #pragma unroll
    for (int n = 0; n < 2; ++n){
      acc[MH*4+m][n] = __builtin_amdgcn_mfma_f32_16x16x32_bf16(
          a[m][0], b[n][0], acc[MH*4+m][n], 0, 0, 0);
      acc[MH*4+m][n] = __builtin_amdgcn_mfma_f32_16x16x32_bf16(
          a[m][1], b[n][1], acc[MH*4+m][n], 0, 0, 0);
    }
  __builtin_amdgcn_s_setprio(0);
}

__global__ __launch_bounds__(512, 2) void gemm_out3(const u16* __restrict__ A,
    const u16* __restrict__ Wo, float* __restrict__ C){
  __shared__ __align__(16) u16 ldsA[2][256*64];  // 64KB
  __shared__ __align__(16) u16 ldsB[2][128*64];  // 32KB
  const int tid = threadIdx.x, w = tid >> 6, lane = tid & 63;
  const int g = lane >> 4, ln = lane & 15;
  const int wr = w >> 2, wc = w & 3;
  const int bid = blockIdx.x;
  const int x = bid & 7, s = bid >> 3;            // XCD-bijective, mt-major
  const int mt = s >> 1, nt = 2*x + (s & 1);
  const int bm = mt*256, bnl = nt << 7;           // BN = 128
  f32x4 acc[8][2];
  {
    const f32x4 z4 = {0.f,0.f,0.f,0.f};
    #pragma unroll
    for (int i = 0; i < 8; ++i){ acc[i][0] = z4; acc[i][1] = z4; }
  }
  stageA (A,  bm,  0, 0, ldsA[0], w, lane);
  stageA (A,  bm,  0, 1, ldsA[0], w, lane);
  stageB3(Wo, bnl, 0,    ldsB[0], w, lane);
  stageA (A,  bm,  1, 0, ldsA[1], w, lane);
  asm volatile("s_waitcnt vmcnt(2)" ::: "memory");
  __builtin_amdgcn_s_barrier();

  bf16x8 a[4][2], b[2][2];
  const int NT = DMODEL/64;   // 32
  for (int t = 0; t < NT; ++t){
    const int cur = t & 1;
    const u16* LA = ldsA[cur];
    const u16* LB = ldsB[cur];
    load_a<0>(a, LA, wr, ln, g);
    load_b3(b, LB, wc, ln, g);
    if (t+1 < NT){
      stageA (A,  bm,  t+1, 1, ldsA[cur^1], w, lane);
      stageB3(Wo, bnl, t+1,    ldsB[cur^1], w, lane);
    }
    phase_pre();
    mfma8x2<0>(acc, a, b);
    __builtin_amdgcn_s_barrier();
    load_a<1>(a, LA, wr, ln, g);
    if (t+2 < NT) stageA(A, bm, t+2, 0, ldsA[cur], w, lane);
    if (t < NT-2) { asm volatile("s_waitcnt vmcnt(2)" ::: "memory"); }
    else          { asm volatile("s_waitcnt vmcnt(0)" ::: "memory"); }
    phase_pre();
    mfma8x2<1>(acc, a, b);
    __builtin_amdgcn_s_barrier();
  }

  #pragma unroll
  for (int mf = 0; mf < 8; ++mf)
    #pragma unroll
    for (int nf = 0; nf < 2; ++nf){
      int col = bnl + wc*32 + nf*16 + ln;
      #pragma unroll
      for (int i = 0; i < 4; ++i){
        int row = bm + wr*128 + mf*16 + g*4 + i;
        C[(size_t)row*DMODEL + col] = acc[mf][nf][i];
      }
    }
}

// ================= causal flash attention v5 (r13 exact, best) ======
__device__ __forceinline__ void attn_stageK(const u16* __restrict__ Kb,
    u16* Kt, int b, int h, int kb, int w, int lane){
  #pragma unroll
  for (int is = 0; is < 4; ++is){
    int o = w*4096 + is*1024 + lane*16;
    int row = o >> 8;                          // K rows: 256B each
    int sc  = ((o >> 4) & 15) ^ (row & 7);
    gload_lds16(Kb + (size_t)(b*SEQ + kb + row)*DMODEL + h*DHEAD + sc*8,
                Kt + w*2048 + is*512);
  }
}
__device__ __forceinline__ void attn_stageV(const u16* __restrict__ Vtb,
    u16* Vt, int bh, int kb, int w, int lane){
  #pragma unroll
  for (int is = 0; is < 4; ++is){
    int o = w*4096 + is*1024 + lane*16;
    int row = o >> 7;                          // V^T rows: 128B each
    int sc  = ((o >> 4) & 7) ^ (row & 7);
    gload_lds16(Vtb + (size_t)(bh*DHEAD + row)*SEQ + kb + sc*8,
                Vt + w*2048 + is*512);
  }
}

template<bool MASKED>
__device__ __forceinline__ void attn_qkt_sm(const u16* Kt, u16* Pw,
    const bf16x8 (&qf)[2][4], f32x4 (&yacc)[2][8],
    float (&mrun)[2], float (&lrun)[2],
    int kb, int qg0, int g, int ln){
  #pragma unroll
  for (int qc = 0; qc < 2; ++qc){
    f32x4 st[4];
    __builtin_amdgcn_s_setprio(1);
    #pragma unroll
    for (int kt = 0; kt < 4; ++kt){
      f32x4 accs = {0.f,0.f,0.f,0.f};
      #pragma unroll
      for (int c = 0; c < 4; ++c){
        int row = kt*16 + ln;
        int ch  = (c*4 + g) ^ (row & 7);
        bf16x8 kf = *reinterpret_cast<const bf16x8*>(Kt + row*128 + ch*8);
        accs = __builtin_amdgcn_mfma_f32_16x16x32_bf16(kf, qf[qc][c], accs, 0, 0, 0);
      }
      st[kt] = accs;
    }
    __builtin_amdgcn_s_setprio(0);

    const int qg = qg0 + qc*16;
    float p[16];
    float tmax = -1e30f;
    #pragma unroll
    for (int kt = 0; kt < 4; ++kt)
      #pragma unroll
      for (int i = 0; i < 4; ++i){
        float s = st[kt][i];
        if (MASKED && (kb + kt*16 + g*4 + i) > qg) s = -1e30f;
        p[kt*4+i] = s;
        tmax = fmaxf(tmax, s);
      }
    tmax = fmaxf(tmax, __shfl_xor(tmax, 16));
    tmax = fmaxf(tmax, __shfl_xor(tmax, 32));

    if (!__all(tmax - mrun[qc] <= 11.5f)){
      float mn = fmaxf(mrun[qc], tmax);
      float fr = __builtin_amdgcn_exp2f(mrun[qc] - mn);
      lrun[qc] *= fr;
      float fi[4];
      #pragma unroll
      for (int i = 0; i < 4; ++i) fi[i] = __shfl(fr, g*4 + i);
      #pragma unroll
      for (int dt = 0; dt < 8; ++dt)
        #pragma unroll
        for (int i = 0; i < 4; ++i) yacc[qc][dt][i] *= fi[i];
      mrun[qc] = mn;
    }
    float psum = 0.f;
    #pragma unroll
    for (int j = 0; j < 16; ++j){
      p[j] = __builtin_amdgcn_exp2f(p[j] - mrun[qc]);
      psum += p[j];
    }
    psum += __shfl_xor(psum, 16);
    psum += __shfl_xor(psum, 32);
    lrun[qc] += psum;

    char* pb = reinterpret_cast<char*>(Pw + qc*1024);
    #pragma unroll
    for (int kt = 0; kt < 4; ++kt)
      #pragma unroll
      for (int pr = 0; pr < 2; ++pr){
        uint32_t pk = (uint32_t)f2bf(p[kt*4 + 2*pr]) |
                      ((uint32_t)f2bf(p[kt*4 + 2*pr + 1]) << 16);
        int byte = (kt*16 + g*4 + 2*pr)*2;
        int ch   = (byte >> 4) ^ (ln & 7);
        int addr = ln*128 + (ch << 4) + (byte & 15);
        *reinterpret_cast<uint32_t*>(pb + addr) = pk;
      }
  }
}

__device__ __forceinline__ void attn_pv(const u16* Vt, const u16* Pw,
                                        f32x4 (&yacc)[2][8], int g, int ln){
  __builtin_amdgcn_s_setprio(1);
  #pragma unroll
  for (int kc = 0; kc < 2; ++kc){
    int chp = (kc*4 + g) ^ (ln & 7);
    bf16x8 pf0 = *reinterpret_cast<const bf16x8*>(Pw +        ln*64 + chp*8);
    bf16x8 pf1 = *reinterpret_cast<const bf16x8*>(Pw + 1024 + ln*64 + chp*8);
    #pragma unroll
    for (int dt = 0; dt < 8; ++dt){
      int row = dt*16 + ln;
      int chv = (kc*4 + g) ^ (row & 7);
      bf16x8 vf = *reinterpret_cast<const bf16x8*>(Vt + row*64 + chv*8);
      yacc[0][dt] = __builtin_amdgcn_mfma_f32_16x16x32_bf16(pf0, vf, yacc[0][dt], 0, 0, 0);
      yacc[1][dt] = __builtin_amdgcn_mfma_f32_16x16x32_bf16(pf1, vf, yacc[1][dt], 0, 0, 0);
    }
  }
  __builtin_amdgcn_s_setprio(0);
}

__global__ __launch_bounds__(256, 2) void attn_fwd(const u16* __restrict__ Qb,
    const u16* __restrict__ Kb, const u16* __restrict__ Vtb, u16* __restrict__ Yb){
  __shared__ __align__(16) u16 Kt[2][64*128];  // 32KB
  __shared__ __align__(16) u16 Vt[2][128*64];  // 32KB
  __shared__ __align__(16) u16 Pl[4][2048];    // 16KB
  const int tid = threadIdx.x, w = tid >> 6, lane = tid & 63;
  const int g = lane >> 4, ln = lane & 15;
  // XCD-chunked mapping (bijective over 512 blocks):
  const int bid = blockIdx.x;
  const int xcd = bid & 7, idx = bid >> 3;
  const int slot = idx >> 4, j = idx & 15;
  const int x = (j & 1) ? (15 - (j >> 1)) : (j >> 1);   // pairs {i,15-i}
  const int bh = (slot < 2) ? (xcd*2 + slot) : (xcd*2 + 14 + slot);
  const int b = bh >> 4, h = bh & 15;
  const int qb = (bh < 16) ? x : (15 - x);              // constant-sum balance
  const int qw = qb*128 + w*32;
  const int qg0 = qw + ln;
  const int NT = 2*qb + 2;

  bf16x8 qf[2][4];
  #pragma unroll
  for (int qc = 0; qc < 2; ++qc){
    const u16* qp = Qb + (size_t)(b*SEQ + qw + qc*16 + ln)*DMODEL + h*DHEAD + g*8;
    #pragma unroll
    for (int c = 0; c < 4; ++c) qf[qc][c] = *reinterpret_cast<const bf16x8*>(qp + c*32);
  }
  float mrun[2] = {-1e30f, -1e30f}, lrun[2] = {0.f, 0.f};
  f32x4 yacc[2][8];
  {
    const f32x4 z4 = {0.f,0.f,0.f,0.f};
    #pragma unroll
    for (int qc = 0; qc < 2; ++qc)
      #pragma unroll
      for (int dt = 0; dt < 8; ++dt) yacc[qc][dt] = z4;
  }
  u16* Pw = &Pl[w][0];

  attn_stageK(Kb, &Kt[0][0], b, h, 0, w, lane);
  attn_stageV(Vtb, &Vt[0][0], bh, 0, w, lane);
  asm volatile("s_waitcnt vmcnt(0)" ::: "memory");
  __builtin_amdgcn_s_barrier();

  int cur = 0;
  for (int t = 0; t < NT; ++t){
    const int kb = t*64;
    if (t+1 < NT){
      attn_stageK(Kb, &Kt[cur^1][0], b, h, kb + 64, w, lane);
      attn_stageV(Vtb, &Vt[cur^1][0], bh, kb + 64, w, lane);
    }
    bool active = true;
    if (t < NT-2){
      attn_qkt_sm<false>(&Kt[cur][0], Pw, qf, yacc, mrun, lrun, kb, qg0, g, ln);
    } else if (t == NT-2){
      if (w >= 2) attn_qkt_sm<false>(&Kt[cur][0], Pw, qf, yacc, mrun, lrun, kb, qg0, g, ln);
      else        attn_qkt_sm<true >(&Kt[cur][0], Pw, qf, yacc, mrun, lrun, kb, qg0, g, ln);
    } else {
      if (w >= 2) attn_qkt_sm<true >(&Kt[cur][0], Pw, qf, yacc, mrun, lrun, kb, qg0, g, ln);
      else        active = false;
    }
    if (active) attn_pv(&Vt[cur][0], Pw, yacc, g, ln);
    asm volatile("s_waitcnt vmcnt(0) lgkmcnt(0)" ::: "memory");
    __builtin_amdgcn_s_barrier();
    cur ^= 1;
  }

  #pragma unroll
  for (int qc = 0; qc < 2; ++qc){
    float inv[4];
    #pragma unroll
    for (int i = 0; i < 4; ++i){
      float li = __shfl(lrun[qc], g*4 + i);
      inv[i] = __builtin_amdgcn_rcpf(li);
    }
    #pragma unroll
    for (int dt = 0; dt < 8; ++dt)
      #pragma unroll
      for (int i = 0; i < 4; ++i){
        Yb[(size_t)(b*SEQ + qw + qc*16 + g*4 + i)*DMODEL + h*DHEAD + dt*16 + ln] =
            f2bf(yacc[qc][dt][i] * inv[i]);
      }
  }
}

// ---------------- launcher ----------------
extern "C" void kernel_launch(void* const* d_in, const int* in_sizes, int n_in,
                              void* d_out, int out_size, void* d_ws, size_t ws_size,
                              hipStream_t stream) {
  const float* x  = (const float*)d_in[0];
  const float* Wq = (const float*)d_in[1];
  const float* Wk = (const float*)d_in[2];
  const float* Wv = (const float*)d_in[3];
  const float* Wo = (const float*)d_in[4];
  float* out = (float*)d_out;

  char* ws = (char*)d_ws;
  u16* xb  = (u16*)(ws +          0);
  u16* Wqb = (u16*)(ws + 16777216);    // Wq/Wk/Wv/Wo contiguous (32MB)
  u16* Wob = (u16*)(ws + 41943040);
  u16* Qb  = (u16*)(ws + 50331648);
  u16* Kb  = (u16*)(ws + 67108864);
  u16* Vtb = (u16*)(ws + 83886080);
  u16* Yb  = (u16*)(ws + 100663296);

  cvt_all<<<dim3(24576), 256, 0, stream>>>(x, Wq, Wk, Wv, Wo, xb);

  gemm_qkv192<<<dim3(512), 512, 0, stream>>>(xb, Wqb, Qb, Kb, Vtb);

  attn_fwd<<<dim3(512), 256, 0, stream>>>(Qb, Kb, Vtb, Yb);

  gemm_out3<<<dim3(256), 512, 0, stream>>>(Yb, Wob, out);
}